// Round 1
// baseline (424.442 us; speedup 1.0000x reference)
//
#include <hip/hip_runtime.h>

#define DIM 128
#define EPSF 1e-5f
#define BK_SHIFT 10
#define BK_NODES 1024
#define BK_CAP 20480   // mean bucket load 16327, sd ~127 -> 32-sigma margin

typedef __attribute__((ext_vector_type(8))) short short8;
typedef __attribute__((ext_vector_type(8))) unsigned short ushort8;
typedef __attribute__((ext_vector_type(4))) float float4v;

__device__ inline unsigned short f2bf(float x) {
    union { float f; unsigned u; } z; z.f = x;
    unsigned u = z.u;
    unsigned r = u + 0x7FFF + ((u >> 16) & 1);   // round-to-nearest-even
    return (unsigned short)(r >> 16);
}
__device__ inline float bf2f(unsigned short u) {
    union { unsigned u; float f; } z; z.u = ((unsigned)u) << 16;
    return z.f;
}

// ---------------------------------------------------------------- CSR build: 2-level counting sort
__global__ void binA_kernel(const int* __restrict__ src, const int* __restrict__ dst,
                            unsigned* __restrict__ barr, int* __restrict__ bcnt,
                            int E, int NB) {
    __shared__ int cnt[64];
    __shared__ int gcur[64];
    int tid = threadIdx.x;
    int tile0 = blockIdx.x * 4096;
    if (tid < 64) cnt[tid] = 0;
    __syncthreads();
    unsigned pk[16]; int bk[16];
#pragma unroll
    for (int i = 0; i < 16; ++i) {
        int e = tile0 + i * 256 + tid;
        if (e < E) {
            int d = dst[e];
            int s = src[e];
            bk[i] = d >> BK_SHIFT;
            pk[i] = ((unsigned)(d & (BK_NODES - 1)) << 16) | (unsigned)s;
            atomicAdd(&cnt[bk[i]], 1);
        } else bk[i] = -1;
    }
    __syncthreads();
    if (tid < 64) {
        int c = (tid < NB) ? cnt[tid] : 0;
        gcur[tid] = (c > 0) ? atomicAdd(&bcnt[tid], c) : 0;
    }
    __syncthreads();
#pragma unroll
    for (int i = 0; i < 16; ++i) {
        if (bk[i] >= 0) {
            int pos = atomicAdd(&gcur[bk[i]], 1);
            if (pos < BK_CAP)
                barr[(size_t)bk[i] * BK_CAP + pos] = pk[i];
        }
    }
}

// Pass B (self-scanning): per-block 49-term prefix of bcnt replaces bucketscan dispatch.
__global__ void binB_kernel(const unsigned* __restrict__ barr, const int* __restrict__ bcnt,
                            int* __restrict__ rowptr, int* __restrict__ colidx,
                            int N, int E, int NB) {
    __shared__ int hist[BK_NODES];
    __shared__ int sm[256];
    __shared__ int bc[64];
    __shared__ int gbS;
    int b = blockIdx.x;
    int tid = threadIdx.x;
    if (tid < 64) bc[tid] = (tid < NB) ? bcnt[tid] : 0;
    __syncthreads();
    if (tid == 0) {
        int run = 0;
        for (int i = 0; i < b; ++i) run += bc[i];
        gbS = run;
        if (b == 0) rowptr[N] = E;
    }
    __syncthreads();
    int cnt = bc[b];
    if (cnt > BK_CAP) cnt = BK_CAP;
    const unsigned* arr = barr + (size_t)b * BK_CAP;
    int gb = gbS;
#pragma unroll
    for (int j = 0; j < 4; ++j) hist[tid * 4 + j] = 0;
    __syncthreads();
    for (int i = tid; i < cnt; i += 256)
        atomicAdd(&hist[arr[i] >> 16], 1);
    __syncthreads();
    int h[4], s = 0;
#pragma unroll
    for (int j = 0; j < 4; ++j) { h[j] = hist[tid * 4 + j]; s += h[j]; }
    sm[tid] = s;
    __syncthreads();
    int tot = s;
    for (int off = 1; off < 256; off <<= 1) {
        int x = (tid >= off) ? sm[tid - off] : 0;
        __syncthreads();
        sm[tid] += x;
        __syncthreads();
    }
    int run = sm[tid] - tot;
#pragma unroll
    for (int j = 0; j < 4; ++j) { hist[tid * 4 + j] = run; run += h[j]; }
    __syncthreads();
    int nbase = b << BK_SHIFT;
    int nn = N - nbase; if (nn > BK_NODES) nn = BK_NODES;
    for (int j = tid; j < nn; j += 256)
        rowptr[nbase + j] = gb + hist[j];
    __syncthreads();
    for (int i = tid; i < cnt; i += 256) {
        unsigned u = arr[i];
        int pos = atomicAdd(&hist[u >> 16], 1);
        colidx[gb + pos] = (int)(u & 0xFFFFu);
    }
}

// ---------------------------------------------------------------- weight pack (fp32 -> bf16, B-fragment-major)
__global__ void packw_kernel(const float* __restrict__ Ws, const float* __restrict__ Wn,
                             unsigned short* __restrict__ wpack) {
    int l = blockIdx.x >> 3;
    int s = blockIdx.x & 7;
    int tid = threadIdx.x;
#pragma unroll
    for (int pi = 0; pi < 2; ++pi) {
        int p = tid * 2 + pi;
        int nt = p >> 6;
        int lane = p & 63;
        int kb = s * 32 + (lane >> 4) * 8;
        int col = nt * 16 + (lane & 15);
        unsigned short* dstp = wpack + (size_t)l * 32768 + ((size_t)(s * 8 + nt) * 64 + lane) * 8;
#pragma unroll
        for (int j = 0; j < 8; ++j) {
            int k = kb + j;
            float v = (k < 128) ? Ws[(size_t)l * 16384 + k * 128 + col]
                                : Wn[(size_t)l * 16384 + (k - 128) * 128 + col];
            dstp[j] = f2bf(v);
        }
    }
}

// ---------------------------------------------------------------- feat -> bf16 Hb (linear [N][128])
__global__ void convert_kernel(const float* __restrict__ feat, unsigned short* __restrict__ Hb,
                               int N) {
    int idx = blockIdx.x * blockDim.x + threadIdx.x;   // float4 units
    if (idx >= N * 32) return;
    float4 v = ((const float4*)feat)[idx];
    ushort4 o;
    o.x = f2bf(v.x); o.y = f2bf(v.y); o.z = f2bf(v.z); o.w = f2bf(v.w);
    ((ushort4*)Hb)[idx] = o;
}

// ---------------------------------------------------------------- FUSED aggregate + MFMA GEMM
// Block = 128 output rows, 4 waves. Each wave aggregates ITS OWN 32 rows into a
// per-wave LDS slice (XOR-swizzled), then runs the MFMA K-loop (self half from
// global Hb, agg half from LDS, B fragments straight from L1/L2-hot wpack).
// No block-wide sync between gather and MFMA: a wave only reads its own slice,
// so MFMA of finished waves overlaps gather latency of the others.
__launch_bounds__(256)
__global__ void fusedgemm_kernel(const unsigned short* __restrict__ Hb,
                                 const int* __restrict__ rowptr,
                                 const int* __restrict__ colidx,
                                 const unsigned short* __restrict__ wpack,
                                 const float* __restrict__ bias,
                                 unsigned short* __restrict__ outb, float* __restrict__ outf,
                                 float* __restrict__ stats, int withStats, int N) {
    __shared__ __align__(16) unsigned short aggT[128 * 128];   // 32 KB, swizzled
    __shared__ float sm[256];
    int tid = threadIdx.x;
    int wave = tid >> 6, lane = tid & 63;
    int row0 = blockIdx.x * 128;
    sm[tid] = 0.f;
    __syncthreads();

    // ---- gather phase: quarter-wave (16 lanes x ushort8 = full 256B row) per node,
    //      4 nodes in flight per wave, no cross-lane reduce needed.
    int q = lane >> 4;        // quarter 0..3
    int ql = lane & 15;
    for (int i = 0; i < 8; ++i) {
        int lrow = (wave << 5) + (q << 3) + i;
        int node = row0 + lrow;
        float a[8];
#pragma unroll
        for (int j = 0; j < 8; ++j) a[j] = 0.f;
        int deg = 1;
        if (node < N) {
            int beg = rowptr[node], end = rowptr[node + 1];
            deg = end - beg;
            int e = beg;
            for (; e + 3 < end; e += 4) {
                int s0 = colidx[e], s1 = colidx[e + 1], s2 = colidx[e + 2], s3 = colidx[e + 3];
                ushort8 u0 = *(const ushort8*)(Hb + (size_t)s0 * 128 + ql * 8);
                ushort8 u1 = *(const ushort8*)(Hb + (size_t)s1 * 128 + ql * 8);
                ushort8 u2 = *(const ushort8*)(Hb + (size_t)s2 * 128 + ql * 8);
                ushort8 u3 = *(const ushort8*)(Hb + (size_t)s3 * 128 + ql * 8);
#pragma unroll
                for (int j = 0; j < 8; ++j)
                    a[j] += (bf2f((unsigned short)u0[j]) + bf2f((unsigned short)u1[j]))
                          + (bf2f((unsigned short)u2[j]) + bf2f((unsigned short)u3[j]));
            }
            for (; e < end; ++e) {
                int s0 = colidx[e];
                ushort8 u0 = *(const ushort8*)(Hb + (size_t)s0 * 128 + ql * 8);
#pragma unroll
                for (int j = 0; j < 8; ++j) a[j] += bf2f((unsigned short)u0[j]);
            }
        }
        float inv = 1.0f / (float)(deg > 0 ? deg : 1);
        ushort8 o;
#pragma unroll
        for (int j = 0; j < 8; ++j) o[j] = f2bf(a[j] * inv);
        unsigned boff = (unsigned)lrow * 256u + (unsigned)ql * 16u;
        boff ^= (unsigned)((lrow & 7) << 4);                      // G4 XOR swizzle
        *(ushort8*)((char*)aggT + boff) = o;
    }
    // no __syncthreads: wave reads only its own 32-row slice below

    // ---- MFMA phase
    int mrow = lane & 15, kq = lane >> 4;
    const unsigned short* Sbase = Hb + (size_t)(row0 + (wave << 5) + mrow) * 128 + kq * 8;

    float4v acc[2][8];
#pragma unroll
    for (int i = 0; i < 2; ++i)
#pragma unroll
        for (int j = 0; j < 8; ++j) acc[i][j] = (float4v){0.f, 0.f, 0.f, 0.f};

#pragma unroll
    for (int s = 0; s < 8; ++s) {
        short8 a0, a1;
        if (s < 4) {                                   // self half: K 0..127 from global Hb
            a0 = *(const short8*)(Sbase + s * 32);
            a1 = *(const short8*)(Sbase + (size_t)16 * 128 + s * 32);
        } else {                                       // agg half: K 128..255 from LDS
            int lr0 = (wave << 5) + mrow;
            int lr1 = lr0 + 16;
            unsigned c = (unsigned)(((s - 4) * 32 + kq * 8) * 2);
            unsigned b0 = (unsigned)lr0 * 256u + c; b0 ^= (unsigned)((lr0 & 7) << 4);
            unsigned b1 = (unsigned)lr1 * 256u + c; b1 ^= (unsigned)((lr1 & 7) << 4);
            a0 = *(const short8*)((const char*)aggT + b0);
            a1 = *(const short8*)((const char*)aggT + b1);
        }
#pragma unroll
        for (int nt = 0; nt < 8; ++nt) {
            short8 b = *(const short8*)(wpack + ((size_t)(s * 8 + nt) * 64 + lane) * 8);
            acc[0][nt] = __builtin_amdgcn_mfma_f32_16x16x32_bf16(a0, b, acc[0][nt], 0, 0, 0);
            acc[1][nt] = __builtin_amdgcn_mfma_f32_16x16x32_bf16(a1, b, acc[1][nt], 0, 0, 0);
        }
    }

    // ---- epilogue: bias + residual (+ stats / fp32 out)
    int colb = lane & 15;
    int rq = (lane >> 4) * 4;              // C layout: col = lane&15, row = (lane>>4)*4 + reg
#pragma unroll
    for (int mt = 0; mt < 2; ++mt) {
        int rowt = row0 + (wave << 5) + mt * 16 + rq;
#pragma unroll
        for (int nt = 0; nt < 8; ++nt) {
            int col = nt * 16 + colb;
            float bv = bias[col];
            float slo = 0.f, qlo = 0.f;
#pragma unroll
            for (int r = 0; r < 4; ++r) {
                int row = rowt + r;
                if (row < N) {
                    float res = bf2f(Hb[(size_t)row * 128 + col]);
                    float v = acc[mt][nt][r] + bv + res;
                    if (withStats) {
                        outb[(size_t)row * 128 + col] = f2bf(v);
                        slo += v; qlo += v * v;
                    } else {
                        outf[(size_t)row * 128 + col] = v;
                    }
                }
            }
            if (withStats) {
                atomicAdd(&sm[col], slo);
                atomicAdd(&sm[128 + col], qlo);
            }
        }
    }
    if (withStats) {
        __syncthreads();
        if (tid < 128) {
            atomicAdd(&stats[tid], sm[tid]);
            atomicAdd(&stats[128 + tid], sm[128 + tid]);
        }
    }
}

// ---------------------------------------------------------------- BN apply + ReLU (bf16 hn -> bf16 Hb, linear)
__global__ void bnapply_kernel(const unsigned short* __restrict__ hn,
                               unsigned short* __restrict__ Hb,
                               const float* __restrict__ stats, const float* __restrict__ gamma,
                               const float* __restrict__ beta, float invN, int N) {
    __shared__ float sc_s[128], sh_s[128];
    int tid = threadIdx.x;
    if (tid < 128) {
        float mean = stats[tid] * invN;
        float var = stats[128 + tid] * invN - mean * mean;
        float sc = gamma[tid] * rsqrtf(var + EPSF);
        sc_s[tid] = sc;
        sh_s[tid] = beta[tid] - mean * sc;
    }
    __syncthreads();
    int idx = blockIdx.x * 256 + tid;      // ushort4 units
    if (idx >= N * 32) return;
    int c4 = idx & 31;
    ushort4 u = *(const ushort4*)(hn + (size_t)idx * 4);
    ushort4 o;
    {
        int col = c4 * 4;
        float v0 = fmaf(bf2f(u.x), sc_s[col], sh_s[col]);
        float v1 = fmaf(bf2f(u.y), sc_s[col + 1], sh_s[col + 1]);
        float v2 = fmaf(bf2f(u.z), sc_s[col + 2], sh_s[col + 2]);
        float v3 = fmaf(bf2f(u.w), sc_s[col + 3], sh_s[col + 3]);
        o.x = f2bf(fmaxf(v0, 0.f));
        o.y = f2bf(fmaxf(v1, 0.f));
        o.z = f2bf(fmaxf(v2, 0.f));
        o.w = f2bf(fmaxf(v3, 0.f));
    }
    *(ushort4*)(Hb + (size_t)idx * 4) = o;
}

// ---------------------------------------------------------------- launch
extern "C" void kernel_launch(void* const* d_in, const int* in_sizes, int n_in,
                              void* d_out, int out_size, void* d_ws, size_t ws_size,
                              hipStream_t stream) {
    const float* feat  = (const float*)d_in[0];
    const int*   src   = (const int*)d_in[1];
    const int*   dst   = (const int*)d_in[2];
    const float* Wself = (const float*)d_in[3];
    const float* Wneig = (const float*)d_in[4];
    const float* bias  = (const float*)d_in[5];
    const float* gamma = (const float*)d_in[6];
    const float* beta  = (const float*)d_in[7];

    int N = in_sizes[0] / DIM;
    int E = in_sizes[1];
    int Npad = (N + 127) & ~127;
    int NB = (N + BK_NODES - 1) >> BK_SHIFT;   // 49 for N=50000 (<=64 required)

    char* ws = (char*)d_ws;
    size_t off = 0;
    auto alloc = [&](size_t bytes) -> void* {
        void* p = ws + off;
        off = (off + bytes + 255) & ~(size_t)255;
        return p;
    };
    unsigned short* Hb     = (unsigned short*)alloc((size_t)Npad * 128 * 2);
    unsigned short* hnS    = (unsigned short*)alloc((size_t)Npad * 128 * 2);
    unsigned short* wpack  = (unsigned short*)alloc((size_t)3 * 32768 * 2);
    int*   colidx = (int*)alloc((size_t)E * 4);
    int*   rowptr = (int*)alloc((size_t)(N + 1) * 4);
    int*   bcnt   = (int*)alloc(64 * 4);          // 256 B -> stats directly follows
    float* stats  = (float*)alloc(512 * 4);       // 2 layers x [sum|sumsq] of 128

    // bucket array aliases Hb (dead before convert_kernel writes Hb)
    unsigned* barr = (unsigned*)Hb;   // NB * BK_CAP * 4 = ~4 MB << 12.8 MB

    // one memset covers bcnt (256 B) + stats (2048 B)
    hipMemsetAsync(bcnt, 0, 64 * 4 + 512 * 4, stream);
    binA_kernel<<<(E + 4095) / 4096, 256, 0, stream>>>(src, dst, barr, bcnt, E, NB);
    binB_kernel<<<NB, 256, 0, stream>>>(barr, bcnt, rowptr, colidx, N, E, NB);

    packw_kernel<<<24, 256, 0, stream>>>(Wself, Wneig, wpack);
    convert_kernel<<<(N * 32 + 255) / 256, 256, 0, stream>>>(feat, Hb, N);
    if (Npad > N)
        hipMemsetAsync(Hb + (size_t)N * 128, 0, (size_t)(Npad - N) * 256, stream);

    float invN = 1.0f / (float)N;

    for (int l = 0; l < 3; ++l) {
        int withStats = (l < 2) ? 1 : 0;
        fusedgemm_kernel<<<Npad / 128, 256, 0, stream>>>(
            Hb, rowptr, colidx, wpack + (size_t)l * 32768, bias + (size_t)l * DIM,
            hnS, (float*)d_out, stats + (size_t)l * 256, withStats, N);
        if (withStats)
            bnapply_kernel<<<(N * 32 + 255) / 256, 256, 0, stream>>>(
                hnS, Hb, stats + (size_t)l * 256, gamma + (size_t)l * DIM,
                beta + (size_t)l * DIM, invN, N);
    }
}

// Round 2
// 361.821 us; speedup vs baseline: 1.1731x; 1.1731x over previous
//
#include <hip/hip_runtime.h>

#define DIM 128
#define EPSF 1e-5f
#define BK_SHIFT 10
#define BK_NODES 1024
#define GRP_SHIFT 13          // src octile: 8192-node window = 2 MB of Hb rows (fits 4 MB XCD L2)
#define NGRP 8
#define BKS_CAP 4352          // per (dst-bucket, src-group): mean 2684, sd ~52 -> 32-sigma margin

typedef __attribute__((ext_vector_type(8))) short short8;
typedef __attribute__((ext_vector_type(4))) float float4v;

__device__ inline unsigned short f2bf(float x) {
    union { float f; unsigned u; } z; z.f = x;
    unsigned u = z.u;
    unsigned r = u + 0x7FFF + ((u >> 16) & 1);   // round-to-nearest-even
    return (unsigned short)(r >> 16);
}
__device__ inline float bf2f(unsigned short u) {
    union { unsigned u; float f; } z; z.u = ((unsigned)u) << 16;
    return z.f;
}

// ---------------------------------------------------------------- CSR build: 2-level counting sort
// Sub-bucket key = (dst-bucket << 3) | src-octile, so binB can emit colidx grouped by
// src octile within every row -> aggregate's resident waves sweep 2 MB src windows
// in the same order (L2-resident gather) instead of random 12.8 MB.
__global__ void binA_kernel(const int* __restrict__ src, const int* __restrict__ dst,
                            unsigned* __restrict__ barr, int* __restrict__ bcnt,
                            int E, int NBS) {
    __shared__ int cnt[512];
    __shared__ int gcur[512];
    int tid = threadIdx.x;
    int tile0 = blockIdx.x * 4096;
    for (int j = tid; j < 512; j += 256) cnt[j] = 0;
    __syncthreads();
    unsigned pk[16]; int bk[16];
#pragma unroll
    for (int i = 0; i < 16; ++i) {
        int e = tile0 + i * 256 + tid;
        if (e < E) {
            int d = dst[e];
            int s = src[e];
            bk[i] = ((d >> BK_SHIFT) << 3) | (s >> GRP_SHIFT);
            pk[i] = ((unsigned)(d & (BK_NODES - 1)) << 16) | (unsigned)s;
            atomicAdd(&cnt[bk[i]], 1);
        } else bk[i] = -1;
    }
    __syncthreads();
    for (int j = tid; j < 512; j += 256) {
        int c = (j < NBS) ? cnt[j] : 0;
        gcur[j] = (c > 0) ? atomicAdd(&bcnt[j], c) : 0;
    }
    __syncthreads();
#pragma unroll
    for (int i = 0; i < 16; ++i) {
        if (bk[i] >= 0) {
            int pos = atomicAdd(&gcur[bk[i]], 1);
            if (pos < BKS_CAP)
                barr[(size_t)bk[i] * BKS_CAP + pos] = pk[i];
        }
    }
}

// Pass B: per-block prefix of sub-bucket counts; hist over all 8 sub-buckets; then
// 8 group-ordered scatter passes (barrier between groups keeps octile ordering stable).
__global__ void binB_kernel(const unsigned* __restrict__ barr, const int* __restrict__ bcnt,
                            int* __restrict__ rowptr, int* __restrict__ colidx,
                            int N, int E, int NBS) {
    __shared__ int hist[BK_NODES];
    __shared__ int sm[256];
    __shared__ int bc[512];
    __shared__ int gbS;
    int b = blockIdx.x;
    int tid = threadIdx.x;
    for (int j = tid; j < 512; j += 256) bc[j] = (j < NBS) ? bcnt[j] : 0;
    __syncthreads();
    if (tid == 0) {
        int run = 0;
        for (int i = 0; i < b * NGRP; ++i) run += bc[i];
        gbS = run;
        if (b == 0) rowptr[N] = E;
    }
    __syncthreads();
    int gb = gbS;
#pragma unroll
    for (int j = 0; j < 4; ++j) hist[tid * 4 + j] = 0;
    __syncthreads();
    for (int g = 0; g < NGRP; ++g) {
        int cg = bc[b * NGRP + g];
        if (cg > BKS_CAP) cg = BKS_CAP;
        const unsigned* arr = barr + (size_t)(b * NGRP + g) * BKS_CAP;
        for (int i = tid; i < cg; i += 256)
            atomicAdd(&hist[arr[i] >> 16], 1);
    }
    __syncthreads();
    int h[4], s = 0;
#pragma unroll
    for (int j = 0; j < 4; ++j) { h[j] = hist[tid * 4 + j]; s += h[j]; }
    sm[tid] = s;
    __syncthreads();
    int tot = s;
    for (int off = 1; off < 256; off <<= 1) {
        int x = (tid >= off) ? sm[tid - off] : 0;
        __syncthreads();
        sm[tid] += x;
        __syncthreads();
    }
    int run = sm[tid] - tot;
#pragma unroll
    for (int j = 0; j < 4; ++j) { hist[tid * 4 + j] = run; run += h[j]; }
    __syncthreads();
    int nbase = b << BK_SHIFT;
    int nn = N - nbase; if (nn > BK_NODES) nn = BK_NODES;
    for (int j = tid; j < nn; j += 256)
        rowptr[nbase + j] = gb + hist[j];
    __syncthreads();
    for (int g = 0; g < NGRP; ++g) {
        int cg = bc[b * NGRP + g];
        if (cg > BKS_CAP) cg = BKS_CAP;
        const unsigned* arr = barr + (size_t)(b * NGRP + g) * BKS_CAP;
        for (int i = tid; i < cg; i += 256) {
            unsigned u = arr[i];
            int pos = atomicAdd(&hist[u >> 16], 1);
            colidx[gb + pos] = (int)(u & 0xFFFFu);
        }
        __syncthreads();
    }
}

// ---------------------------------------------------------------- weight pack (fp32 -> bf16, B-fragment-major)
__global__ void packw_kernel(const float* __restrict__ Ws, const float* __restrict__ Wn,
                             unsigned short* __restrict__ wpack) {
    int l = blockIdx.x >> 3;
    int s = blockIdx.x & 7;
    int tid = threadIdx.x;
#pragma unroll
    for (int pi = 0; pi < 2; ++pi) {
        int p = tid * 2 + pi;
        int nt = p >> 6;
        int lane = p & 63;
        int kb = s * 32 + (lane >> 4) * 8;
        int col = nt * 16 + (lane & 15);
        unsigned short* dstp = wpack + (size_t)l * 32768 + ((size_t)(s * 8 + nt) * 64 + lane) * 8;
#pragma unroll
        for (int j = 0; j < 8; ++j) {
            int k = kb + j;
            float v = (k < 128) ? Ws[(size_t)l * 16384 + k * 128 + col]
                                : Wn[(size_t)l * 16384 + (k - 128) * 128 + col];
            dstp[j] = f2bf(v);
        }
    }
}

// ---------------------------------------------------------------- feat -> bf16 into Acat h-half
__global__ void convert_kernel(const float* __restrict__ feat, unsigned short* __restrict__ Acat,
                               int N) {
    int idx = blockIdx.x * blockDim.x + threadIdx.x;   // float4 units
    if (idx >= N * 32) return;
    float4 v = ((const float4*)feat)[idx];
    int r = idx >> 5, c4 = idx & 31;
    ushort4 o;
    o.x = f2bf(v.x); o.y = f2bf(v.y); o.z = f2bf(v.z); o.w = f2bf(v.w);
    ((ushort4*)Acat)[(size_t)r * 64 + c4] = o;
}

// ---------------------------------------------------------------- mean aggregation (bf16 in, bf16 out)
// ONE WAVE per node (R6-proven mapping); half-wave (32 lanes x ushort4) per neighbor row,
// unroll-4 per half (8 rows in flight per wave). Block 0 zeroes stats (replaces memset).
__global__ void aggregate_kernel(unsigned short* Acat, const int* __restrict__ rowptr,
                                 const int* __restrict__ colidx, float* __restrict__ stats,
                                 int N) {
    if (blockIdx.x == 0) stats[threadIdx.x] = 0.f;   // 256 threads -> stats[0..255]
    int wid = (blockIdx.x * blockDim.x + threadIdx.x) >> 6;
    if (wid >= N) return;
    int lane = threadIdx.x & 63;
    int half = lane >> 5, sl = lane & 31;
    int beg = rowptr[wid], end = rowptr[wid + 1];
    float4 acc = make_float4(0.f, 0.f, 0.f, 0.f);
    int e = beg + half;
    for (; e + 6 < end; e += 8) {
        int s0 = colidx[e];
        int s1 = colidx[e + 2];
        int s2 = colidx[e + 4];
        int s3 = colidx[e + 6];
        ushort4 u0 = *(const ushort4*)(Acat + (size_t)s0 * 256 + sl * 4);
        ushort4 u1 = *(const ushort4*)(Acat + (size_t)s1 * 256 + sl * 4);
        ushort4 u2 = *(const ushort4*)(Acat + (size_t)s2 * 256 + sl * 4);
        ushort4 u3 = *(const ushort4*)(Acat + (size_t)s3 * 256 + sl * 4);
        acc.x += (bf2f(u0.x) + bf2f(u1.x)) + (bf2f(u2.x) + bf2f(u3.x));
        acc.y += (bf2f(u0.y) + bf2f(u1.y)) + (bf2f(u2.y) + bf2f(u3.y));
        acc.z += (bf2f(u0.z) + bf2f(u1.z)) + (bf2f(u2.z) + bf2f(u3.z));
        acc.w += (bf2f(u0.w) + bf2f(u1.w)) + (bf2f(u2.w) + bf2f(u3.w));
    }
    for (; e < end; e += 2) {
        int s0 = colidx[e];
        ushort4 u0 = *(const ushort4*)(Acat + (size_t)s0 * 256 + sl * 4);
        acc.x += bf2f(u0.x);
        acc.y += bf2f(u0.y);
        acc.z += bf2f(u0.z);
        acc.w += bf2f(u0.w);
    }
    acc.x += __shfl_xor(acc.x, 32);
    acc.y += __shfl_xor(acc.y, 32);
    acc.z += __shfl_xor(acc.z, 32);
    acc.w += __shfl_xor(acc.w, 32);
    if (half == 0) {
        int deg = end - beg;
        float inv = 1.0f / (float)(deg > 0 ? deg : 1);
        ushort4 o;
        o.x = f2bf(acc.x * inv); o.y = f2bf(acc.y * inv);
        o.z = f2bf(acc.z * inv); o.w = f2bf(acc.w * inv);
        *(ushort4*)(Acat + (size_t)wid * 256 + 128 + sl * 4) = o;
    }
}

// ---------------------------------------------------------------- MFMA GEMM: Acat(Nx256 bf16) @ Wcat(256x128 bf16)
// + bias + bf16 residual (Acat h-half). withStats: write bf16 hn + column stats;
// else (final layer) write fp32 to outf.
__launch_bounds__(256)
__global__ void gemm_kernel(const unsigned short* __restrict__ Acat,
                            const unsigned short* __restrict__ wpack,
                            const float* __restrict__ bias,
                            unsigned short* __restrict__ outb, float* __restrict__ outf,
                            float* __restrict__ stats, int withStats, int N) {
    __shared__ unsigned short Bs[32768];   // 64 KB, fragment-major
    int tid = threadIdx.x;
    {
        const float4* wsrc = (const float4*)wpack;
        float4* bdst = (float4*)Bs;
#pragma unroll
        for (int i = 0; i < 16; ++i) bdst[i * 256 + tid] = wsrc[i * 256 + tid];
    }
    __syncthreads();

    int wave = tid >> 6, lane = tid & 63;
    int row0 = blockIdx.x * 128 + wave * 32;
    int mrow = lane & 15, kq = lane >> 4;
    const unsigned short* Abase = Acat + (size_t)(row0 + mrow) * 256 + kq * 8;

    float4v acc[2][8];
#pragma unroll
    for (int i = 0; i < 2; ++i)
#pragma unroll
        for (int j = 0; j < 8; ++j) acc[i][j] = (float4v){0.f, 0.f, 0.f, 0.f};

#pragma unroll
    for (int s = 0; s < 8; ++s) {
        short8 a0 = *(const short8*)(Abase + s * 32);
        short8 a1 = *(const short8*)(Abase + 16 * 256 + s * 32);
#pragma unroll
        for (int nt = 0; nt < 8; ++nt) {
            short8 b = *(const short8*)(Bs + ((size_t)(s * 8 + nt) * 64 + lane) * 8);
            acc[0][nt] = __builtin_amdgcn_mfma_f32_16x16x32_bf16(a0, b, acc[0][nt], 0, 0, 0);
            acc[1][nt] = __builtin_amdgcn_mfma_f32_16x16x32_bf16(a1, b, acc[1][nt], 0, 0, 0);
        }
    }

    float* sm = (float*)Bs;
    if (withStats) {
        __syncthreads();
        sm[tid] = 0.f;
        __syncthreads();
    }

    int colb = lane & 15;
    int rq = (lane >> 4) * 4;              // C layout: col = lane&15, row = (lane>>4)*4 + reg
#pragma unroll
    for (int mt = 0; mt < 2; ++mt) {
        int rowt = row0 + mt * 16 + rq;
#pragma unroll
        for (int nt = 0; nt < 8; ++nt) {
            int col = nt * 16 + colb;
            float bv = bias[col];
            float slo = 0.f, qlo = 0.f;
#pragma unroll
            for (int r = 0; r < 4; ++r) {
                int row = rowt + r;
                if (row < N) {
                    float res = bf2f(Acat[(size_t)row * 256 + col]);
                    float v = acc[mt][nt][r] + bv + res;
                    if (withStats) {
                        outb[(size_t)row * 128 + col] = f2bf(v);
                        slo += v; qlo += v * v;
                    } else {
                        outf[(size_t)row * 128 + col] = v;
                    }
                }
            }
            if (withStats) {
                atomicAdd(&sm[col], slo);
                atomicAdd(&sm[128 + col], qlo);
            }
        }
    }
    if (withStats) {
        __syncthreads();
        if (tid < 128) {
            atomicAdd(&stats[tid], sm[tid]);
            atomicAdd(&stats[128 + tid], sm[128 + tid]);
        }
    }
}

// ---------------------------------------------------------------- BN apply + ReLU (bf16 hn -> bf16 Acat h-half)
// scale/shift recomputed per block from raw stats (absorbs bnprep)
__global__ void bnapply_kernel(const unsigned short* __restrict__ hn,
                               unsigned short* __restrict__ Acat,
                               const float* __restrict__ stats, const float* __restrict__ gamma,
                               const float* __restrict__ beta, float invN, int N) {
    __shared__ float sc_s[128], sh_s[128];
    int tid = threadIdx.x;
    if (tid < 128) {
        float mean = stats[tid] * invN;
        float var = stats[128 + tid] * invN - mean * mean;
        float sc = gamma[tid] * rsqrtf(var + EPSF);
        sc_s[tid] = sc;
        sh_s[tid] = beta[tid] - mean * sc;
    }
    __syncthreads();
    int idx = blockIdx.x * 256 + tid;      // ushort4 units
    if (idx >= N * 32) return;
    int row = idx >> 5, c4 = idx & 31;
    ushort4 u = *(const ushort4*)(hn + (size_t)idx * 4);
    ushort4 o;
    {
        int col = c4 * 4;
        float v0 = fmaf(bf2f(u.x), sc_s[col], sh_s[col]);
        float v1 = fmaf(bf2f(u.y), sc_s[col + 1], sh_s[col + 1]);
        float v2 = fmaf(bf2f(u.z), sc_s[col + 2], sh_s[col + 2]);
        float v3 = fmaf(bf2f(u.w), sc_s[col + 3], sh_s[col + 3]);
        o.x = f2bf(fmaxf(v0, 0.f));
        o.y = f2bf(fmaxf(v1, 0.f));
        o.z = f2bf(fmaxf(v2, 0.f));
        o.w = f2bf(fmaxf(v3, 0.f));
    }
    *(ushort4*)(Acat + (size_t)row * 256 + c4 * 4) = o;
}

// ---------------------------------------------------------------- launch
extern "C" void kernel_launch(void* const* d_in, const int* in_sizes, int n_in,
                              void* d_out, int out_size, void* d_ws, size_t ws_size,
                              hipStream_t stream) {
    const float* feat  = (const float*)d_in[0];
    const int*   src   = (const int*)d_in[1];
    const int*   dst   = (const int*)d_in[2];
    const float* Wself = (const float*)d_in[3];
    const float* Wneig = (const float*)d_in[4];
    const float* bias  = (const float*)d_in[5];
    const float* gamma = (const float*)d_in[6];
    const float* beta  = (const float*)d_in[7];

    int N = in_sizes[0] / DIM;
    int E = in_sizes[1];
    int Npad = (N + 127) & ~127;
    int NB = (N + BK_NODES - 1) >> BK_SHIFT;   // 49 for N=50000 (<=64 required)
    int NBS = NB * NGRP;                       // 392 sub-buckets (<=512)

    char* ws = (char*)d_ws;
    size_t off = 0;
    auto alloc = [&](size_t bytes) -> void* {
        void* p = ws + off;
        off = (off + bytes + 255) & ~(size_t)255;
        return p;
    };
    unsigned short* Acat   = (unsigned short*)alloc((size_t)Npad * 256 * 2);
    unsigned short* hnS    = (unsigned short*)alloc((size_t)Npad * 128 * 2);
    unsigned short* wpack  = (unsigned short*)alloc((size_t)3 * 32768 * 2);
    int*   colidx = (int*)alloc((size_t)E * 4);
    int*   rowptr = (int*)alloc((size_t)(N + 1) * 4);
    int*   bcnt   = (int*)alloc(512 * 4);
    float* stats  = (float*)alloc(256 * 4);

    // bucket array aliases Acat (dead before convert_kernel writes Acat)
    unsigned* barr = (unsigned*)Acat;   // NBS * BKS_CAP * 4 = ~6.8 MB << 25.6 MB

    // CSR build: 2-level counting sort with src-octile sub-buckets
    hipMemsetAsync(bcnt, 0, 512 * 4, stream);
    binA_kernel<<<(E + 4095) / 4096, 256, 0, stream>>>(src, dst, barr, bcnt, E, NBS);
    binB_kernel<<<NB, 256, 0, stream>>>(barr, bcnt, rowptr, colidx, N, E, NBS);

    // weight pack + input convert + zero pad rows of Acat
    packw_kernel<<<24, 256, 0, stream>>>(Wself, Wneig, wpack);
    convert_kernel<<<(N * 32 + 255) / 256, 256, 0, stream>>>(feat, Acat, N);
    if (Npad > N)
        hipMemsetAsync(Acat + (size_t)N * 256, 0, (size_t)(Npad - N) * 512, stream);

    float invN = 1.0f / (float)N;

    for (int l = 0; l < 3; ++l) {
        aggregate_kernel<<<(N + 3) / 4, 256, 0, stream>>>(Acat, rowptr, colidx, stats, N);
        int withStats = (l < 2) ? 1 : 0;
        gemm_kernel<<<Npad / 128, 256, 0, stream>>>(
            Acat, wpack + (size_t)l * 32768, bias + (size_t)l * DIM,
            hnS, (float*)d_out, stats, withStats, N);
        if (withStats)
            bnapply_kernel<<<(N * 32 + 255) / 256, 256, 0, stream>>>(
                hnS, Acat, stats, gamma + (size_t)l * DIM, beta + (size_t)l * DIM, invN, N);
    }
}

// Round 3
// 335.862 us; speedup vs baseline: 1.2637x; 1.0773x over previous
//
#include <hip/hip_runtime.h>

#define DIM 128
#define EPSF 1e-5f
#define BK_SHIFT 8            // 256 dst nodes per bucket -> 196 binB blocks (was 49: latency-bound)
#define BK_NODES 256
#define GRP_SHIFT 13          // src octile: 8192-node window = 2 MB of Acat rows (fits 4 MB XCD L2)
#define NGRP 8
#define BKS_CAP 1536          // per (dst-bucket, src-octile): mean 671, sd ~26 -> 32-sigma margin
#define MAXNBS 1600

typedef __attribute__((ext_vector_type(8))) short short8;
typedef __attribute__((ext_vector_type(4))) float float4v;

__device__ inline unsigned short f2bf(float x) {
    union { float f; unsigned u; } z; z.f = x;
    unsigned u = z.u;
    unsigned r = u + 0x7FFF + ((u >> 16) & 1);   // round-to-nearest-even
    return (unsigned short)(r >> 16);
}
__device__ inline float bf2f(unsigned short u) {
    union { unsigned u; float f; } z; z.u = ((unsigned)u) << 16;
    return z.f;
}

// ---------------------------------------------------------------- CSR build: 2-level counting sort
// Sub-bucket key = (dst-bucket << 3) | src-octile, so binB can emit colidx grouped by
// src octile within every row -> aggregate's resident waves sweep 2 MB src windows
// in the same order (L2-resident gather) instead of random 12.8 MB.
__global__ void binA_kernel(const int* __restrict__ src, const int* __restrict__ dst,
                            unsigned* __restrict__ barr, int* __restrict__ bcnt,
                            int E, int NBS) {
    __shared__ int cnt[MAXNBS];
    __shared__ int gcur[MAXNBS];
    int tid = threadIdx.x;
    int tile0 = blockIdx.x * 4096;
    for (int j = tid; j < NBS; j += 256) cnt[j] = 0;
    __syncthreads();
    unsigned pk[16]; int bk[16];
#pragma unroll
    for (int i = 0; i < 16; ++i) {
        int e = tile0 + i * 256 + tid;
        if (e < E) {
            int d = dst[e];
            int s = src[e];
            bk[i] = ((d >> BK_SHIFT) << 3) | (s >> GRP_SHIFT);
            pk[i] = ((unsigned)(d & (BK_NODES - 1)) << 16) | (unsigned)s;
            atomicAdd(&cnt[bk[i]], 1);
        } else bk[i] = -1;
    }
    __syncthreads();
    for (int j = tid; j < NBS; j += 256) {
        int c = cnt[j];
        gcur[j] = (c > 0) ? atomicAdd(&bcnt[j], c) : 0;
    }
    __syncthreads();
#pragma unroll
    for (int i = 0; i < 16; ++i) {
        if (bk[i] >= 0) {
            int pos = atomicAdd(&gcur[bk[i]], 1);
            if (pos < BKS_CAP)
                barr[(size_t)bk[i] * BKS_CAP + pos] = pk[i];
        }
    }
}

// Pass B: one block per 256-node dst bucket. Parallel tree-reduce of the global base,
// per-node hist (1 node / thread), scan, then 8 group-ordered scatter passes.
__global__ void binB_kernel(const unsigned* __restrict__ barr, const int* __restrict__ bcnt,
                            int* __restrict__ rowptr, int* __restrict__ colidx,
                            int N, int E, int NBS) {
    __shared__ int hist[256];
    __shared__ int sm[256];
    __shared__ int bc[NGRP];
    int b = blockIdx.x;
    int tid = threadIdx.x;
    int lim = b * NGRP;
    // parallel prefix: gb = sum(bcnt[0 .. b*NGRP))
    int part = 0;
    for (int i = tid; i < lim; i += 256) part += bcnt[i];
    sm[tid] = part;
    if (tid < NGRP) bc[tid] = bcnt[lim + tid];
    __syncthreads();
    for (int off = 128; off > 0; off >>= 1) {
        if (tid < off) sm[tid] += sm[tid + off];
        __syncthreads();
    }
    int gb = sm[0];
    if (b == 0 && tid == 0) rowptr[N] = E;
    __syncthreads();
    hist[tid] = 0;
    __syncthreads();
    for (int g = 0; g < NGRP; ++g) {
        int cg = bc[g]; if (cg > BKS_CAP) cg = BKS_CAP;
        const unsigned* arr = barr + (size_t)(b * NGRP + g) * BKS_CAP;
        for (int i = tid; i < cg; i += 256)
            atomicAdd(&hist[arr[i] >> 16], 1);
    }
    __syncthreads();
    int h = hist[tid];
    sm[tid] = h;
    __syncthreads();
    for (int off = 1; off < 256; off <<= 1) {
        int x = (tid >= off) ? sm[tid - off] : 0;
        __syncthreads();
        sm[tid] += x;
        __syncthreads();
    }
    int base = sm[tid] - h;                 // exclusive scan
    hist[tid] = base;
    int node = (b << BK_SHIFT) + tid;
    if (node < N) rowptr[node] = gb + base;
    __syncthreads();
    for (int g = 0; g < NGRP; ++g) {
        int cg = bc[g]; if (cg > BKS_CAP) cg = BKS_CAP;
        const unsigned* arr = barr + (size_t)(b * NGRP + g) * BKS_CAP;
        for (int i = tid; i < cg; i += 256) {
            unsigned u = arr[i];
            int pos = atomicAdd(&hist[u >> 16], 1);
            colidx[gb + pos] = (int)(u & 0xFFFFu);
        }
        __syncthreads();
    }
}

// ---------------------------------------------------------------- weight pack (fp32 -> bf16, B-fragment-major)
__global__ void packw_kernel(const float* __restrict__ Ws, const float* __restrict__ Wn,
                             unsigned short* __restrict__ wpack) {
    int l = blockIdx.x >> 3;
    int s = blockIdx.x & 7;
    int tid = threadIdx.x;
#pragma unroll
    for (int pi = 0; pi < 2; ++pi) {
        int p = tid * 2 + pi;
        int nt = p >> 6;
        int lane = p & 63;
        int kb = s * 32 + (lane >> 4) * 8;
        int col = nt * 16 + (lane & 15);
        unsigned short* dstp = wpack + (size_t)l * 32768 + ((size_t)(s * 8 + nt) * 64 + lane) * 8;
#pragma unroll
        for (int j = 0; j < 8; ++j) {
            int k = kb + j;
            float v = (k < 128) ? Ws[(size_t)l * 16384 + k * 128 + col]
                                : Wn[(size_t)l * 16384 + (k - 128) * 128 + col];
            dstp[j] = f2bf(v);
        }
    }
}

// ---------------------------------------------------------------- feat -> bf16 into Acat h-half
__global__ void convert_kernel(const float* __restrict__ feat, unsigned short* __restrict__ Acat,
                               int N) {
    int idx = blockIdx.x * blockDim.x + threadIdx.x;   // float4 units
    if (idx >= N * 32) return;
    float4 v = ((const float4*)feat)[idx];
    int r = idx >> 5, c4 = idx & 31;
    ushort4 o;
    o.x = f2bf(v.x); o.y = f2bf(v.y); o.z = f2bf(v.z); o.w = f2bf(v.w);
    ((ushort4*)Acat)[(size_t)r * 64 + c4] = o;
}

// ---------------------------------------------------------------- mean aggregation (bf16 in, bf16 out)
// ONE WAVE per node; half-wave (32 lanes x ushort4) per neighbor row,
// unroll-4 per half (8 rows in flight per wave). Block 0 zeroes stats (replaces memset).
__global__ void aggregate_kernel(unsigned short* Acat, const int* __restrict__ rowptr,
                                 const int* __restrict__ colidx, float* __restrict__ stats,
                                 int N) {
    if (blockIdx.x == 0) stats[threadIdx.x] = 0.f;   // 256 threads -> stats[0..255]
    int wid = (blockIdx.x * blockDim.x + threadIdx.x) >> 6;
    if (wid >= N) return;
    int lane = threadIdx.x & 63;
    int half = lane >> 5, sl = lane & 31;
    int beg = rowptr[wid], end = rowptr[wid + 1];
    float4 acc = make_float4(0.f, 0.f, 0.f, 0.f);
    int e = beg + half;
    for (; e + 6 < end; e += 8) {
        int s0 = colidx[e];
        int s1 = colidx[e + 2];
        int s2 = colidx[e + 4];
        int s3 = colidx[e + 6];
        ushort4 u0 = *(const ushort4*)(Acat + (size_t)s0 * 256 + sl * 4);
        ushort4 u1 = *(const ushort4*)(Acat + (size_t)s1 * 256 + sl * 4);
        ushort4 u2 = *(const ushort4*)(Acat + (size_t)s2 * 256 + sl * 4);
        ushort4 u3 = *(const ushort4*)(Acat + (size_t)s3 * 256 + sl * 4);
        acc.x += (bf2f(u0.x) + bf2f(u1.x)) + (bf2f(u2.x) + bf2f(u3.x));
        acc.y += (bf2f(u0.y) + bf2f(u1.y)) + (bf2f(u2.y) + bf2f(u3.y));
        acc.z += (bf2f(u0.z) + bf2f(u1.z)) + (bf2f(u2.z) + bf2f(u3.z));
        acc.w += (bf2f(u0.w) + bf2f(u1.w)) + (bf2f(u2.w) + bf2f(u3.w));
    }
    for (; e < end; e += 2) {
        int s0 = colidx[e];
        ushort4 u0 = *(const ushort4*)(Acat + (size_t)s0 * 256 + sl * 4);
        acc.x += bf2f(u0.x);
        acc.y += bf2f(u0.y);
        acc.z += bf2f(u0.z);
        acc.w += bf2f(u0.w);
    }
    acc.x += __shfl_xor(acc.x, 32);
    acc.y += __shfl_xor(acc.y, 32);
    acc.z += __shfl_xor(acc.z, 32);
    acc.w += __shfl_xor(acc.w, 32);
    if (half == 0) {
        int deg = end - beg;
        float inv = 1.0f / (float)(deg > 0 ? deg : 1);
        ushort4 o;
        o.x = f2bf(acc.x * inv); o.y = f2bf(acc.y * inv);
        o.z = f2bf(acc.z * inv); o.w = f2bf(acc.w * inv);
        *(ushort4*)(Acat + (size_t)wid * 256 + 128 + sl * 4) = o;
    }
}

// ---------------------------------------------------------------- MFMA GEMM: Acat(Nx256 bf16) @ Wcat(256x128 bf16)
// + bias + bf16 residual (Acat h-half). withStats: write bf16 hn + column stats;
// else (final layer) write fp32 to outf.
__launch_bounds__(256)
__global__ void gemm_kernel(const unsigned short* __restrict__ Acat,
                            const unsigned short* __restrict__ wpack,
                            const float* __restrict__ bias,
                            unsigned short* __restrict__ outb, float* __restrict__ outf,
                            float* __restrict__ stats, int withStats, int N) {
    __shared__ unsigned short Bs[32768];   // 64 KB, fragment-major
    int tid = threadIdx.x;
    {
        const float4* wsrc = (const float4*)wpack;
        float4* bdst = (float4*)Bs;
#pragma unroll
        for (int i = 0; i < 16; ++i) bdst[i * 256 + tid] = wsrc[i * 256 + tid];
    }
    __syncthreads();

    int wave = tid >> 6, lane = tid & 63;
    int row0 = blockIdx.x * 128 + wave * 32;
    int mrow = lane & 15, kq = lane >> 4;
    const unsigned short* Abase = Acat + (size_t)(row0 + mrow) * 256 + kq * 8;

    float4v acc[2][8];
#pragma unroll
    for (int i = 0; i < 2; ++i)
#pragma unroll
        for (int j = 0; j < 8; ++j) acc[i][j] = (float4v){0.f, 0.f, 0.f, 0.f};

#pragma unroll
    for (int s = 0; s < 8; ++s) {
        short8 a0 = *(const short8*)(Abase + s * 32);
        short8 a1 = *(const short8*)(Abase + 16 * 256 + s * 32);
#pragma unroll
        for (int nt = 0; nt < 8; ++nt) {
            short8 b = *(const short8*)(Bs + ((size_t)(s * 8 + nt) * 64 + lane) * 8);
            acc[0][nt] = __builtin_amdgcn_mfma_f32_16x16x32_bf16(a0, b, acc[0][nt], 0, 0, 0);
            acc[1][nt] = __builtin_amdgcn_mfma_f32_16x16x32_bf16(a1, b, acc[1][nt], 0, 0, 0);
        }
    }

    float* sm = (float*)Bs;
    if (withStats) {
        __syncthreads();
        sm[tid] = 0.f;
        __syncthreads();
    }

    int colb = lane & 15;
    int rq = (lane >> 4) * 4;              // C layout: col = lane&15, row = (lane>>4)*4 + reg
#pragma unroll
    for (int mt = 0; mt < 2; ++mt) {
        int rowt = row0 + mt * 16 + rq;
#pragma unroll
        for (int nt = 0; nt < 8; ++nt) {
            int col = nt * 16 + colb;
            float bv = bias[col];
            float slo = 0.f, qlo = 0.f;
#pragma unroll
            for (int r = 0; r < 4; ++r) {
                int row = rowt + r;
                if (row < N) {
                    float res = bf2f(Acat[(size_t)row * 256 + col]);
                    float v = acc[mt][nt][r] + bv + res;
                    if (withStats) {
                        outb[(size_t)row * 128 + col] = f2bf(v);
                        slo += v; qlo += v * v;
                    } else {
                        outf[(size_t)row * 128 + col] = v;
                    }
                }
            }
            if (withStats) {
                atomicAdd(&sm[col], slo);
                atomicAdd(&sm[128 + col], qlo);
            }
        }
    }
    if (withStats) {
        __syncthreads();
        if (tid < 128) {
            atomicAdd(&stats[tid], sm[tid]);
            atomicAdd(&stats[128 + tid], sm[128 + tid]);
        }
    }
}

// ---------------------------------------------------------------- BN apply + ReLU (bf16 hn -> bf16 Acat h-half)
__global__ void bnapply_kernel(const unsigned short* __restrict__ hn,
                               unsigned short* __restrict__ Acat,
                               const float* __restrict__ stats, const float* __restrict__ gamma,
                               const float* __restrict__ beta, float invN, int N) {
    __shared__ float sc_s[128], sh_s[128];
    int tid = threadIdx.x;
    if (tid < 128) {
        float mean = stats[tid] * invN;
        float var = stats[128 + tid] * invN - mean * mean;
        float sc = gamma[tid] * rsqrtf(var + EPSF);
        sc_s[tid] = sc;
        sh_s[tid] = beta[tid] - mean * sc;
    }
    __syncthreads();
    int idx = blockIdx.x * 256 + tid;      // ushort4 units
    if (idx >= N * 32) return;
    int row = idx >> 5, c4 = idx & 31;
    ushort4 u = *(const ushort4*)(hn + (size_t)idx * 4);
    ushort4 o;
    {
        int col = c4 * 4;
        float v0 = fmaf(bf2f(u.x), sc_s[col], sh_s[col]);
        float v1 = fmaf(bf2f(u.y), sc_s[col + 1], sh_s[col + 1]);
        float v2 = fmaf(bf2f(u.z), sc_s[col + 2], sh_s[col + 2]);
        float v3 = fmaf(bf2f(u.w), sc_s[col + 3], sh_s[col + 3]);
        o.x = f2bf(fmaxf(v0, 0.f));
        o.y = f2bf(fmaxf(v1, 0.f));
        o.z = f2bf(fmaxf(v2, 0.f));
        o.w = f2bf(fmaxf(v3, 0.f));
    }
    *(ushort4*)(Acat + (size_t)row * 256 + c4 * 4) = o;
}

// ---------------------------------------------------------------- launch
extern "C" void kernel_launch(void* const* d_in, const int* in_sizes, int n_in,
                              void* d_out, int out_size, void* d_ws, size_t ws_size,
                              hipStream_t stream) {
    const float* feat  = (const float*)d_in[0];
    const int*   src   = (const int*)d_in[1];
    const int*   dst   = (const int*)d_in[2];
    const float* Wself = (const float*)d_in[3];
    const float* Wneig = (const float*)d_in[4];
    const float* bias  = (const float*)d_in[5];
    const float* gamma = (const float*)d_in[6];
    const float* beta  = (const float*)d_in[7];

    int N = in_sizes[0] / DIM;
    int E = in_sizes[1];
    int Npad = (N + 127) & ~127;
    int NB = (N + BK_NODES - 1) >> BK_SHIFT;   // 196 for N=50000
    int NBS = NB * NGRP;                       // 1568 sub-buckets (<=1600)

    char* ws = (char*)d_ws;
    size_t off = 0;
    auto alloc = [&](size_t bytes) -> void* {
        void* p = ws + off;
        off = (off + bytes + 255) & ~(size_t)255;
        return p;
    };
    unsigned short* Acat   = (unsigned short*)alloc((size_t)Npad * 256 * 2);
    unsigned short* hnS    = (unsigned short*)alloc((size_t)Npad * 128 * 2);
    unsigned short* wpack  = (unsigned short*)alloc((size_t)3 * 32768 * 2);
    int*   colidx = (int*)alloc((size_t)E * 4);
    int*   rowptr = (int*)alloc((size_t)(N + 1) * 4);
    int*   bcnt   = (int*)alloc(MAXNBS * 4);
    float* stats  = (float*)alloc(256 * 4);

    // bucket array aliases Acat (dead before convert_kernel writes Acat)
    unsigned* barr = (unsigned*)Acat;   // NBS * BKS_CAP * 4 = ~9.6 MB << 25.6 MB

    // CSR build: 2-level counting sort with src-octile sub-buckets
    hipMemsetAsync(bcnt, 0, MAXNBS * 4, stream);
    binA_kernel<<<(E + 4095) / 4096, 256, 0, stream>>>(src, dst, barr, bcnt, E, NBS);
    binB_kernel<<<NB, 256, 0, stream>>>(barr, bcnt, rowptr, colidx, N, E, NBS);

    // weight pack + input convert + zero pad rows of Acat
    packw_kernel<<<24, 256, 0, stream>>>(Wself, Wneig, wpack);
    convert_kernel<<<(N * 32 + 255) / 256, 256, 0, stream>>>(feat, Acat, N);
    if (Npad > N)
        hipMemsetAsync(Acat + (size_t)N * 256, 0, (size_t)(Npad - N) * 512, stream);

    float invN = 1.0f / (float)N;

    for (int l = 0; l < 3; ++l) {
        aggregate_kernel<<<(N + 3) / 4, 256, 0, stream>>>(Acat, rowptr, colidx, stats, N);
        int withStats = (l < 2) ? 1 : 0;
        gemm_kernel<<<Npad / 128, 256, 0, stream>>>(
            Acat, wpack + (size_t)l * 32768, bias + (size_t)l * DIM,
            hnS, (float*)d_out, stats, withStats, N);
        if (withStats)
            bnapply_kernel<<<(N * 32 + 255) / 256, 256, 0, stream>>>(
                hnS, Acat, stats, gamma + (size_t)l * DIM, beta + (size_t)l * DIM, invN, N);
    }
}

// Round 4
// 325.505 us; speedup vs baseline: 1.3040x; 1.0318x over previous
//
#include <hip/hip_runtime.h>

#define DIM 128
#define EPSF 1e-5f
#define BK_SHIFT 8            // 256 dst nodes per bucket -> 196 binB blocks
#define BK_NODES 256
#define GRP_SHIFT 13          // src octile: 8192-node window; Hd rows dense -> 2 MB window
#define NGRP 8
#define BKS_CAP 1536          // per (dst-bucket, src-octile): mean 671, +32 sigma
#define MAXNBS 1600

typedef __attribute__((ext_vector_type(8))) short short8;
typedef __attribute__((ext_vector_type(4))) float float4v;

__device__ inline unsigned short f2bf(float x) {
    union { float f; unsigned u; } z; z.f = x;
    unsigned u = z.u;
    unsigned r = u + 0x7FFF + ((u >> 16) & 1);   // round-to-nearest-even
    return (unsigned short)(r >> 16);
}
__device__ inline float bf2f(unsigned short u) {
    union { unsigned u; float f; } z; z.u = ((unsigned)u) << 16;
    return z.f;
}

// ---------------------------------------------------------------- CSR build: 2-level counting sort
__global__ void binA_kernel(const int* __restrict__ src, const int* __restrict__ dst,
                            unsigned* __restrict__ barr, int* __restrict__ bcnt,
                            int E, int NBS) {
    __shared__ int cnt[MAXNBS];
    __shared__ int gcur[MAXNBS];
    int tid = threadIdx.x;
    int tile0 = blockIdx.x * 4096;
    for (int j = tid; j < NBS; j += 256) cnt[j] = 0;
    __syncthreads();
    unsigned pk[16]; int bk[16];
#pragma unroll
    for (int i = 0; i < 16; ++i) {
        int e = tile0 + i * 256 + tid;
        if (e < E) {
            int d = dst[e];
            int s = src[e];
            bk[i] = ((d >> BK_SHIFT) << 3) | (s >> GRP_SHIFT);
            pk[i] = ((unsigned)(d & (BK_NODES - 1)) << 16) | (unsigned)s;
            atomicAdd(&cnt[bk[i]], 1);
        } else bk[i] = -1;
    }
    __syncthreads();
    for (int j = tid; j < NBS; j += 256) {
        int c = cnt[j];
        gcur[j] = (c > 0) ? atomicAdd(&bcnt[j], c) : 0;
    }
    __syncthreads();
#pragma unroll
    for (int i = 0; i < 16; ++i) {
        if (bk[i] >= 0) {
            int pos = atomicAdd(&gcur[bk[i]], 1);
            if (pos < BKS_CAP)
                barr[(size_t)bk[i] * BKS_CAP + pos] = pk[i];
        }
    }
}

// Pass B: one block per 256-node dst bucket; parallel prefix, per-node hist (1 node/thread),
// scan, then 8 group-ordered scatter passes.
__global__ void binB_kernel(const unsigned* __restrict__ barr, const int* __restrict__ bcnt,
                            int* __restrict__ rowptr, int* __restrict__ colidx,
                            int N, int E, int NBS) {
    __shared__ int hist[256];
    __shared__ int sm[256];
    __shared__ int bc[NGRP];
    int b = blockIdx.x;
    int tid = threadIdx.x;
    int lim = b * NGRP;
    int part = 0;
    for (int i = tid; i < lim; i += 256) part += bcnt[i];
    sm[tid] = part;
    if (tid < NGRP) bc[tid] = bcnt[lim + tid];
    __syncthreads();
    for (int off = 128; off > 0; off >>= 1) {
        if (tid < off) sm[tid] += sm[tid + off];
        __syncthreads();
    }
    int gb = sm[0];
    if (b == 0 && tid == 0) rowptr[N] = E;
    __syncthreads();
    hist[tid] = 0;
    __syncthreads();
    for (int g = 0; g < NGRP; ++g) {
        int cg = bc[g]; if (cg > BKS_CAP) cg = BKS_CAP;
        const unsigned* arr = barr + (size_t)(b * NGRP + g) * BKS_CAP;
        for (int i = tid; i < cg; i += 256)
            atomicAdd(&hist[arr[i] >> 16], 1);
    }
    __syncthreads();
    int h = hist[tid];
    sm[tid] = h;
    __syncthreads();
    for (int off = 1; off < 256; off <<= 1) {
        int x = (tid >= off) ? sm[tid - off] : 0;
        __syncthreads();
        sm[tid] += x;
        __syncthreads();
    }
    int base = sm[tid] - h;
    hist[tid] = base;
    int node = (b << BK_SHIFT) + tid;
    if (node < N) rowptr[node] = gb + base;
    __syncthreads();
    for (int g = 0; g < NGRP; ++g) {
        int cg = bc[g]; if (cg > BKS_CAP) cg = BKS_CAP;
        const unsigned* arr = barr + (size_t)(b * NGRP + g) * BKS_CAP;
        for (int i = tid; i < cg; i += 256) {
            unsigned u = arr[i];
            int pos = atomicAdd(&hist[u >> 16], 1);
            colidx[gb + pos] = (int)(u & 0xFFFFu);
        }
        __syncthreads();
    }
}

// ---------------------------------------------------------------- prep: weight pack (blocks 0..23)
// + feat fp32 -> bf16 dense Hd (blocks 24..)
__global__ void prep_kernel(const float* __restrict__ Ws, const float* __restrict__ Wn,
                            unsigned short* __restrict__ wpack,
                            const float* __restrict__ feat, unsigned short* __restrict__ Hd,
                            int N) {
    int b = blockIdx.x;
    int tid = threadIdx.x;
    if (b < 24) {
        int l = b >> 3;
        int s = b & 7;
#pragma unroll
        for (int pi = 0; pi < 2; ++pi) {
            int p = tid * 2 + pi;
            int nt = p >> 6;
            int lane = p & 63;
            int kb = s * 32 + (lane >> 4) * 8;
            int col = nt * 16 + (lane & 15);
            unsigned short* dstp = wpack + (size_t)l * 32768 + ((size_t)(s * 8 + nt) * 64 + lane) * 8;
#pragma unroll
            for (int j = 0; j < 8; ++j) {
                int k = kb + j;
                float v = (k < 128) ? Ws[(size_t)l * 16384 + k * 128 + col]
                                    : Wn[(size_t)l * 16384 + (k - 128) * 128 + col];
                dstp[j] = f2bf(v);
            }
        }
        return;
    }
    int idx = (b - 24) * 256 + tid;    // float4 units
    if (idx >= N * 32) return;
    float4 v = ((const float4*)feat)[idx];
    ushort4 o;
    o.x = f2bf(v.x); o.y = f2bf(v.y); o.z = f2bf(v.z); o.w = f2bf(v.w);
    ((ushort4*)Hd)[idx] = o;
}

// ---------------------------------------------------------------- aggregate (+ fused BN/ReLU apply)
// ONE WAVE per node. Gathers raw rows from dense Hd [N][128] bf16; if BN, applies
// relu(x*sc+sh) per gathered element (sc/sh from raw stats of the previous gemm).
// Each wave also writes its own node's (BN'd) h row into Acat h-half for the GEMM
// self/residual path, and the mean into the agg-half. Replaces the bnapply pass.
template<int BN>
__global__ void aggregate_kernel(const unsigned short* __restrict__ Hd,
                                 unsigned short* __restrict__ Acat,
                                 const int* __restrict__ rowptr,
                                 const int* __restrict__ colidx,
                                 const float* __restrict__ stats,
                                 const float* __restrict__ gamma,
                                 const float* __restrict__ beta,
                                 float invN, int N) {
    int wid = (blockIdx.x * blockDim.x + threadIdx.x) >> 6;
    if (wid >= N) return;
    int lane = threadIdx.x & 63;
    int half = lane >> 5, sl = lane & 31;
    float sc[4], sh[4];
    if (BN) {
#pragma unroll
        for (int j = 0; j < 4; ++j) {
            int c = sl * 4 + j;
            float mean = stats[c] * invN;
            float var = stats[128 + c] * invN - mean * mean;
            float s = gamma[c] * rsqrtf(var + EPSF);
            sc[j] = s; sh[j] = beta[c] - mean * s;
        }
    }
#define BNOP0(x) fmaxf(fmaf(bf2f(x), sc[0], sh[0]), 0.f)
#define BNOP1(x) fmaxf(fmaf(bf2f(x), sc[1], sh[1]), 0.f)
#define BNOP2(x) fmaxf(fmaf(bf2f(x), sc[2], sh[2]), 0.f)
#define BNOP3(x) fmaxf(fmaf(bf2f(x), sc[3], sh[3]), 0.f)
    int beg = rowptr[wid], end = rowptr[wid + 1];
    float4 acc = make_float4(0.f, 0.f, 0.f, 0.f);
    int e = beg + half;
    for (; e + 6 < end; e += 8) {
        int s0 = colidx[e];
        int s1 = colidx[e + 2];
        int s2 = colidx[e + 4];
        int s3 = colidx[e + 6];
        ushort4 u0 = *(const ushort4*)(Hd + (size_t)s0 * 128 + sl * 4);
        ushort4 u1 = *(const ushort4*)(Hd + (size_t)s1 * 128 + sl * 4);
        ushort4 u2 = *(const ushort4*)(Hd + (size_t)s2 * 128 + sl * 4);
        ushort4 u3 = *(const ushort4*)(Hd + (size_t)s3 * 128 + sl * 4);
        if (BN) {
            acc.x += (BNOP0(u0.x) + BNOP0(u1.x)) + (BNOP0(u2.x) + BNOP0(u3.x));
            acc.y += (BNOP1(u0.y) + BNOP1(u1.y)) + (BNOP1(u2.y) + BNOP1(u3.y));
            acc.z += (BNOP2(u0.z) + BNOP2(u1.z)) + (BNOP2(u2.z) + BNOP2(u3.z));
            acc.w += (BNOP3(u0.w) + BNOP3(u1.w)) + (BNOP3(u2.w) + BNOP3(u3.w));
        } else {
            acc.x += (bf2f(u0.x) + bf2f(u1.x)) + (bf2f(u2.x) + bf2f(u3.x));
            acc.y += (bf2f(u0.y) + bf2f(u1.y)) + (bf2f(u2.y) + bf2f(u3.y));
            acc.z += (bf2f(u0.z) + bf2f(u1.z)) + (bf2f(u2.z) + bf2f(u3.z));
            acc.w += (bf2f(u0.w) + bf2f(u1.w)) + (bf2f(u2.w) + bf2f(u3.w));
        }
    }
    for (; e < end; e += 2) {
        int s0 = colidx[e];
        ushort4 u0 = *(const ushort4*)(Hd + (size_t)s0 * 128 + sl * 4);
        if (BN) {
            acc.x += BNOP0(u0.x);
            acc.y += BNOP1(u0.y);
            acc.z += BNOP2(u0.z);
            acc.w += BNOP3(u0.w);
        } else {
            acc.x += bf2f(u0.x);
            acc.y += bf2f(u0.y);
            acc.z += bf2f(u0.z);
            acc.w += bf2f(u0.w);
        }
    }
    acc.x += __shfl_xor(acc.x, 32);
    acc.y += __shfl_xor(acc.y, 32);
    acc.z += __shfl_xor(acc.z, 32);
    acc.w += __shfl_xor(acc.w, 32);
    if (half == 0) {
        int deg = end - beg;
        float inv = 1.0f / (float)(deg > 0 ? deg : 1);
        // own h row (BN'd) -> Acat h-half for the GEMM self/residual path
        ushort4 hrow = *(const ushort4*)(Hd + (size_t)wid * 128 + sl * 4);
        ushort4 ho;
        if (BN) {
            ho.x = f2bf(BNOP0(hrow.x));
            ho.y = f2bf(BNOP1(hrow.y));
            ho.z = f2bf(BNOP2(hrow.z));
            ho.w = f2bf(BNOP3(hrow.w));
        } else ho = hrow;
        *(ushort4*)(Acat + (size_t)wid * 256 + sl * 4) = ho;
        ushort4 o;
        o.x = f2bf(acc.x * inv); o.y = f2bf(acc.y * inv);
        o.z = f2bf(acc.z * inv); o.w = f2bf(acc.w * inv);
        *(ushort4*)(Acat + (size_t)wid * 256 + 128 + sl * 4) = o;
    }
#undef BNOP0
#undef BNOP1
#undef BNOP2
#undef BNOP3
}

// ---------------------------------------------------------------- MFMA GEMM: Acat(Nx256 bf16) @ Wcat(256x128 bf16)
// + bias + bf16 residual (Acat h-half). withStats: write bf16 hn to Hd + column stats
// into the layer's stats slot (pre-zeroed); else write fp32 to outf.
__launch_bounds__(256)
__global__ void gemm_kernel(const unsigned short* __restrict__ Acat,
                            const unsigned short* __restrict__ wpack,
                            const float* __restrict__ bias,
                            unsigned short* __restrict__ outb, float* __restrict__ outf,
                            float* __restrict__ stats, int withStats, int N) {
    __shared__ unsigned short Bs[32768];   // 64 KB, fragment-major
    int tid = threadIdx.x;
    {
        const float4* wsrc = (const float4*)wpack;
        float4* bdst = (float4*)Bs;
#pragma unroll
        for (int i = 0; i < 16; ++i) bdst[i * 256 + tid] = wsrc[i * 256 + tid];
    }
    __syncthreads();

    int wave = tid >> 6, lane = tid & 63;
    int row0 = blockIdx.x * 128 + wave * 32;
    int mrow = lane & 15, kq = lane >> 4;
    const unsigned short* Abase = Acat + (size_t)(row0 + mrow) * 256 + kq * 8;

    float4v acc[2][8];
#pragma unroll
    for (int i = 0; i < 2; ++i)
#pragma unroll
        for (int j = 0; j < 8; ++j) acc[i][j] = (float4v){0.f, 0.f, 0.f, 0.f};

#pragma unroll
    for (int s = 0; s < 8; ++s) {
        short8 a0 = *(const short8*)(Abase + s * 32);
        short8 a1 = *(const short8*)(Abase + 16 * 256 + s * 32);
#pragma unroll
        for (int nt = 0; nt < 8; ++nt) {
            short8 b = *(const short8*)(Bs + ((size_t)(s * 8 + nt) * 64 + lane) * 8);
            acc[0][nt] = __builtin_amdgcn_mfma_f32_16x16x32_bf16(a0, b, acc[0][nt], 0, 0, 0);
            acc[1][nt] = __builtin_amdgcn_mfma_f32_16x16x32_bf16(a1, b, acc[1][nt], 0, 0, 0);
        }
    }

    float* sm = (float*)Bs;
    if (withStats) {
        __syncthreads();
        sm[tid] = 0.f;
        __syncthreads();
    }

    int colb = lane & 15;
    int rq = (lane >> 4) * 4;              // C layout: col = lane&15, row = (lane>>4)*4 + reg
#pragma unroll
    for (int mt = 0; mt < 2; ++mt) {
        int rowt = row0 + mt * 16 + rq;
#pragma unroll
        for (int nt = 0; nt < 8; ++nt) {
            int col = nt * 16 + colb;
            float bv = bias[col];
            float slo = 0.f, qlo = 0.f;
#pragma unroll
            for (int r = 0; r < 4; ++r) {
                int row = rowt + r;
                if (row < N) {
                    float res = bf2f(Acat[(size_t)row * 256 + col]);
                    float v = acc[mt][nt][r] + bv + res;
                    if (withStats) {
                        outb[(size_t)row * 128 + col] = f2bf(v);
                        slo += v; qlo += v * v;
                    } else {
                        outf[(size_t)row * 128 + col] = v;
                    }
                }
            }
            if (withStats) {
                atomicAdd(&sm[col], slo);
                atomicAdd(&sm[128 + col], qlo);
            }
        }
    }
    if (withStats) {
        __syncthreads();
        if (tid < 128) {
            atomicAdd(&stats[tid], sm[tid]);
            atomicAdd(&stats[128 + tid], sm[128 + tid]);
        }
    }
}

// ---------------------------------------------------------------- launch
extern "C" void kernel_launch(void* const* d_in, const int* in_sizes, int n_in,
                              void* d_out, int out_size, void* d_ws, size_t ws_size,
                              hipStream_t stream) {
    const float* feat  = (const float*)d_in[0];
    const int*   src   = (const int*)d_in[1];
    const int*   dst   = (const int*)d_in[2];
    const float* Wself = (const float*)d_in[3];
    const float* Wneig = (const float*)d_in[4];
    const float* bias  = (const float*)d_in[5];
    const float* gamma = (const float*)d_in[6];
    const float* beta  = (const float*)d_in[7];

    int N = in_sizes[0] / DIM;
    int E = in_sizes[1];
    int Npad = (N + 127) & ~127;
    int NB = (N + BK_NODES - 1) >> BK_SHIFT;   // 196 for N=50000
    int NBS = NB * NGRP;                       // 1568 sub-buckets (<=1600)

    char* ws = (char*)d_ws;
    size_t off = 0;
    auto alloc = [&](size_t bytes) -> void* {
        void* p = ws + off;
        off = (off + bytes + 255) & ~(size_t)255;
        return p;
    };
    unsigned short* Acat   = (unsigned short*)alloc((size_t)Npad * 256 * 2);
    unsigned short* Hd     = (unsigned short*)alloc((size_t)Npad * 128 * 2);   // dense h/hn
    unsigned short* wpack  = (unsigned short*)alloc((size_t)3 * 32768 * 2);
    int*   colidx = (int*)alloc((size_t)E * 4);
    int*   rowptr = (int*)alloc((size_t)(N + 1) * 4);
    int*   bcnt   = (int*)alloc(MAXNBS * 4);   // 6400 B (256-mult) -> stats contiguous
    float* stats  = (float*)alloc(512 * 4);    // 2 layer slots of [sum|sumsq]x128

    // bucket array aliases Acat (dead before aggregate writes Acat)
    unsigned* barr = (unsigned*)Acat;   // NBS * BKS_CAP * 4 = ~9.6 MB << 25.7 MB

    // one memset covers bcnt + both stats slots (contiguous)
    hipMemsetAsync(bcnt, 0, MAXNBS * 4 + 512 * 4, stream);
    binA_kernel<<<(E + 4095) / 4096, 256, 0, stream>>>(src, dst, barr, bcnt, E, NBS);
    binB_kernel<<<NB, 256, 0, stream>>>(barr, bcnt, rowptr, colidx, N, E, NBS);

    // weight pack + input convert (dense Hd), one kernel
    prep_kernel<<<24 + (N * 32 + 255) / 256, 256, 0, stream>>>(Wself, Wneig, wpack, feat, Hd, N);

    float invN = 1.0f / (float)N;
    int nagg = (N + 3) / 4;

    // layer 0
    aggregate_kernel<0><<<nagg, 256, 0, stream>>>(Hd, Acat, rowptr, colidx,
                                                  stats, gamma, beta, invN, N);
    gemm_kernel<<<Npad / 128, 256, 0, stream>>>(Acat, wpack, bias, Hd, (float*)d_out,
                                                stats, 1, N);
    // layer 1
    aggregate_kernel<1><<<nagg, 256, 0, stream>>>(Hd, Acat, rowptr, colidx,
                                                  stats, gamma, beta, invN, N);
    gemm_kernel<<<Npad / 128, 256, 0, stream>>>(Acat, wpack + 32768, bias + DIM, Hd,
                                                (float*)d_out, stats + 256, 1, N);
    // layer 2 (final: fp32 out, no stats)
    aggregate_kernel<1><<<nagg, 256, 0, stream>>>(Hd, Acat, rowptr, colidx,
                                                  stats + 256, gamma + DIM, beta + DIM, invN, N);
    gemm_kernel<<<Npad / 128, 256, 0, stream>>>(Acat, wpack + 2 * 32768, bias + 2 * DIM, Hd,
                                                (float*)d_out, stats, 0, N);
}